// Round 5
// baseline (623.542 us; speedup 1.0000x reference)
//
#include <hip/hip_runtime.h>
#include <hip/hip_cooperative_groups.h>
#include <math.h>

namespace cg = cooperative_groups;

#define NN   100000
#define NE   1600000
#define IND  128
#define OUTD 64

// ---------------- ws layout (4-byte words) ----------------
#define OFF_Z      0                          // NN*OUTD bf16 = NN*32 words
#define OFF_SSRC   (OFF_Z + NN * OUTD / 2)    // NN f32
#define OFF_SDST   (OFF_SSRC + NN)            // NN f32
#define OFF_COUNT  (OFF_SDST + NN)            // NN i32
#define OFF_OFS    (OFF_COUNT + NN)           // NN i32
#define OFF_PAY    (OFF_OFS + NN)             // NE i32: src id, sorted by dst
#define OFF_SUMS   (OFF_PAY + NE)             // 128 i32
// total ~= 21 MB

// fused CSR kernel geometry
#define CSR_BLOCKS  1024
#define CSR_THREADS 256
#define CSR_STRIDE  (CSR_BLOCKS * CSR_THREADS)          // 262144
#define EPT         ((NE + CSR_STRIDE - 1) / CSR_STRIDE) // 7
#define SCAN_BLKS   98                                   // 98*1024 >= NN

__device__ __forceinline__ unsigned short f32_to_bf16_rne(float x)
{
    unsigned int b = __float_as_uint(x);
    b += 0x7FFFu + ((b >> 16) & 1u);
    return (unsigned short)(b >> 16);
}

// ---------------- z = h@W (bf16 out), s_src = z.a_src, s_dst = z.a_dst ----------------
// Block = 256 threads = 64 rows x 4 col-groups of 16. h tile staged in LDS.
__global__ void __launch_bounds__(256) k_zs(
    const float* __restrict__ h, const float* __restrict__ W,
    const float* __restrict__ a, unsigned short* __restrict__ z16,
    float* __restrict__ s_src, float* __restrict__ s_dst)
{
    __shared__ float4 tile[64 * 33];      // 64 rows, 32 float4 + 1 pad
    int tid = threadIdx.x;
    int base = blockIdx.x * 64;

    const float4* hg = reinterpret_cast<const float4*>(h);
#pragma unroll
    for (int i = 0; i < 8; ++i) {
        int fidx = i * 256 + tid;         // 0..2047
        int r = fidx >> 5;
        int c = fidx & 31;
        float4 v = make_float4(0.f, 0.f, 0.f, 0.f);
        if (base + r < NN) v = hg[(base + r) * 32 + c];
        tile[r * 33 + c] = v;
    }
    __syncthreads();

    int row = tid & 63;
    int cg_ = tid >> 6;
    int cgu = __builtin_amdgcn_readfirstlane(cg_);
    const float* Wc = W + cgu * 16;

    float acc[16];
#pragma unroll
    for (int j = 0; j < 16; ++j) acc[j] = 0.f;

#pragma unroll 8
    for (int k4 = 0; k4 < 32; ++k4) {
        float4 hv = tile[row * 33 + k4];
        const float* w = Wc + k4 * 4 * OUTD;
#pragma unroll
        for (int kk = 0; kk < 4; ++kk) {
            float hk = (&hv.x)[kk];
#pragma unroll
            for (int j = 0; j < 16; ++j)
                acc[j] = fmaf(hk, w[kk * OUTD + j], acc[j]);
        }
    }

    float s1 = 0.f, s2 = 0.f;
#pragma unroll
    for (int j = 0; j < 16; ++j) {
        s1 = fmaf(acc[j], a[cgu * 16 + j], s1);
        s2 = fmaf(acc[j], a[OUTD + cgu * 16 + j], s2);
    }

    __syncthreads();
    float* red = reinterpret_cast<float*>(tile);
    red[tid] = s1;
    red[256 + tid] = s2;
    __syncthreads();
    if (tid < 64 && base + tid < NN) {
        float t1 = red[tid] + red[tid + 64] + red[tid + 128] + red[tid + 192];
        float t2 = red[256 + tid] + red[256 + tid + 64] + red[256 + tid + 128] + red[256 + tid + 192];
        s_src[base + tid] = t1;
        s_dst[base + tid] = t2;
    }

    // store bf16 z slice: 16 cols -> 8 packed uints -> 2 uint4 stores
    if (base + row < NN) {
        unsigned int u[8];
#pragma unroll
        for (int p = 0; p < 8; ++p) {
            unsigned int lo = f32_to_bf16_rne(acc[2 * p]);
            unsigned int hi = f32_to_bf16_rne(acc[2 * p + 1]);
            u[p] = lo | (hi << 16);
        }
        unsigned short* zp = z16 + (base + row) * OUTD + cgu * 16;
        uint4* z4 = reinterpret_cast<uint4*>(zp);
        z4[0] = make_uint4(u[0], u[1], u[2], u[3]);
        z4[1] = make_uint4(u[4], u[5], u[6], u[7]);
    }
}

// ---------------- fused CSR build: hist + scan + scatter (cooperative) ----------------
__global__ void __launch_bounds__(CSR_THREADS) k_csr(
    const int* __restrict__ src, const int* __restrict__ dst,
    int* __restrict__ count, int* __restrict__ ofs,
    int* __restrict__ pay, int* __restrict__ sums)
{
    cg::grid_group grid = cg::this_grid();
    __shared__ int tmp[CSR_THREADS];
    int t = threadIdx.x;
    int gtid = blockIdx.x * CSR_THREADS + t;

    // phase 1: histogram + per-edge rank kept in registers
    int dv[EPT], sv[EPT], rv[EPT];
#pragma unroll
    for (int i = 0; i < EPT; ++i) {
        int e = gtid + i * CSR_STRIDE;
        if (e < NE) {
            dv[i] = dst[e];
            sv[i] = src[e];
            rv[i] = atomicAdd(&count[dv[i]], 1);
        } else { dv[i] = 0; sv[i] = 0; rv[i] = -1; }
    }
    grid.sync();

    // phase 2: block-level scan (blocks 0..97, 1024 counts each, 4 per thread)
    int idx = blockIdx.x * 1024 + t * 4;
    if (blockIdx.x < SCAN_BLKS) {
        int c0 = (idx + 0 < NN) ? count[idx + 0] : 0;
        int c1 = (idx + 1 < NN) ? count[idx + 1] : 0;
        int c2 = (idx + 2 < NN) ? count[idx + 2] : 0;
        int c3 = (idx + 3 < NN) ? count[idx + 3] : 0;
        int loc = c0 + c1 + c2 + c3;
        tmp[t] = loc;
        __syncthreads();
        for (int off = 1; off < CSR_THREADS; off <<= 1) {
            int x = (t >= off) ? tmp[t - off] : 0;
            __syncthreads();
            tmp[t] += x;
            __syncthreads();
        }
        int excl = tmp[t] - loc;
        if (idx + 0 < NN) ofs[idx + 0] = excl;
        if (idx + 1 < NN) ofs[idx + 1] = excl + c0;
        if (idx + 2 < NN) ofs[idx + 2] = excl + c0 + c1;
        if (idx + 3 < NN) ofs[idx + 3] = excl + c0 + c1 + c2;
        if (t == CSR_THREADS - 1) sums[blockIdx.x] = tmp[t];
    }
    grid.sync();

    // phase 3: scan the 98 block sums (block 0)
    if (blockIdx.x == 0) {
        int v = (t < SCAN_BLKS) ? sums[t] : 0;
        tmp[t] = v;
        __syncthreads();
        for (int off = 1; off < CSR_THREADS; off <<= 1) {
            int x = (t >= off) ? tmp[t - off] : 0;
            __syncthreads();
            tmp[t] += x;
            __syncthreads();
        }
        if (t < SCAN_BLKS) sums[t] = tmp[t] - v;   // exclusive
    }
    grid.sync();

    // phase 4: add block offsets
    if (blockIdx.x < SCAN_BLKS) {
        int add = sums[blockIdx.x];
        if (idx + 0 < NN) ofs[idx + 0] += add;
        if (idx + 1 < NN) ofs[idx + 1] += add;
        if (idx + 2 < NN) ofs[idx + 2] += add;
        if (idx + 3 < NN) ofs[idx + 3] += add;
    }
    grid.sync();

    // phase 5: scatter src ids (rank already in registers)
#pragma unroll
    for (int i = 0; i < EPT; ++i) {
        int e = gtid + i * CSR_STRIDE;
        if (e < NE) pay[ofs[dv[i]] + rv[i]] = sv[i];
    }
}

// ---------------- per-node softmax + aggregate (one wave per node) ----------------
__global__ void __launch_bounds__(256) k_node(
    const unsigned short* __restrict__ z16, const int* __restrict__ pay,
    const float* __restrict__ s_src, const float* __restrict__ s_dst,
    const int* __restrict__ ofs, const int* __restrict__ count,
    float* __restrict__ out)
{
    int gtid = blockIdx.x * 256 + threadIdx.x;
    int w = gtid >> 6;          // node id
    int lane = threadIdx.x & 63;
    if (w >= NN) return;

    int d = count[w];
    int start = ofs[w];
    if (d == 0) {
        out[w * OUTD + lane] = 0.f;
        return;
    }
    float sdst = s_dst[w];

    float acc = 0.f;            // lane owns output column `lane`
    float m = -INFINITY, l = 0.f;

    for (int c = 0; c < d; c += 64) {
        int rem = d - c; if (rem > 64) rem = 64;

        float ev = -INFINITY;
        int rowoff = 0;
        if (lane < rem) {
            int sid = pay[start + c + lane];     // coalesced 4B
            rowoff = sid * OUTD;
            float e0 = s_src[sid] + sdst;        // random 4B gather, L2-resident
            ev = e0 > 0.f ? e0 : 0.01f * e0;     // leaky_relu
        }

        float cmax = ev;
#pragma unroll
        for (int mm = 32; mm; mm >>= 1) cmax = fmaxf(cmax, __shfl_xor(cmax, mm, 64));
        float newm = fmaxf(m, cmax);
        float scale = __expf(m - newm);          // first chunk: exp(-inf)=0
        float ex = (lane < rem) ? __expf(ev - newm) : 0.f;
        float csum = ex;
#pragma unroll
        for (int mm = 32; mm; mm >>= 1) csum += __shfl_xor(csum, mm, 64);
        l = l * scale + csum;
        acc *= scale;
        m = newm;

        // aggregate chunk: 8-way unrolled bf16 gather of z rows for MLP
        int t = 0;
        for (; t + 8 <= rem; t += 8) {
            int r0 = __shfl(rowoff, t + 0, 64), r1 = __shfl(rowoff, t + 1, 64);
            int r2 = __shfl(rowoff, t + 2, 64), r3 = __shfl(rowoff, t + 3, 64);
            int r4 = __shfl(rowoff, t + 4, 64), r5 = __shfl(rowoff, t + 5, 64);
            int r6 = __shfl(rowoff, t + 6, 64), r7 = __shfl(rowoff, t + 7, 64);
            float e0 = __shfl(ex, t + 0, 64), e1 = __shfl(ex, t + 1, 64);
            float e2 = __shfl(ex, t + 2, 64), e3 = __shfl(ex, t + 3, 64);
            float e4 = __shfl(ex, t + 4, 64), e5 = __shfl(ex, t + 5, 64);
            float e6 = __shfl(ex, t + 6, 64), e7 = __shfl(ex, t + 7, 64);
            float v0 = __uint_as_float((unsigned int)z16[r0 + lane] << 16);
            float v1 = __uint_as_float((unsigned int)z16[r1 + lane] << 16);
            float v2 = __uint_as_float((unsigned int)z16[r2 + lane] << 16);
            float v3 = __uint_as_float((unsigned int)z16[r3 + lane] << 16);
            float v4 = __uint_as_float((unsigned int)z16[r4 + lane] << 16);
            float v5 = __uint_as_float((unsigned int)z16[r5 + lane] << 16);
            float v6 = __uint_as_float((unsigned int)z16[r6 + lane] << 16);
            float v7 = __uint_as_float((unsigned int)z16[r7 + lane] << 16);
            acc = fmaf(e0, v0, acc); acc = fmaf(e1, v1, acc);
            acc = fmaf(e2, v2, acc); acc = fmaf(e3, v3, acc);
            acc = fmaf(e4, v4, acc); acc = fmaf(e5, v5, acc);
            acc = fmaf(e6, v6, acc); acc = fmaf(e7, v7, acc);
        }
        for (; t < rem; ++t) {
            int r = __shfl(rowoff, t, 64);
            float e0 = __shfl(ex, t, 64);
            float v = __uint_as_float((unsigned int)z16[r + lane] << 16);
            acc = fmaf(e0, v, acc);
        }
    }

    out[w * OUTD + lane] = acc * (1.f / l);
}

// ---------------- launcher ----------------
extern "C" void kernel_launch(void* const* d_in, const int* in_sizes, int n_in,
                              void* d_out, int out_size, void* d_ws, size_t ws_size,
                              hipStream_t stream)
{
    const float* h   = (const float*)d_in[0];
    const float* W   = (const float*)d_in[1];
    const float* a   = (const float*)d_in[2];
    const int*   src = (const int*)d_in[3];
    const int*   dst = (const int*)d_in[4];
    float* out = (float*)d_out;

    int* ws_i = (int*)d_ws;

    unsigned short* z16 = (unsigned short*)(ws_i + OFF_Z);
    float* s_src  = (float*)(ws_i + OFF_SSRC);
    float* s_dst  = (float*)(ws_i + OFF_SDST);
    int*   count  = ws_i + OFF_COUNT;
    int*   ofs    = ws_i + OFF_OFS;
    int*   pay    = ws_i + OFF_PAY;
    int*   sums   = ws_i + OFF_SUMS;

    // z (bf16), s_src, s_dst
    k_zs<<<(NN + 63) / 64, 256, 0, stream>>>(h, W, a, z16, s_src, s_dst);

    // fused CSR build (cooperative: hist + scan + scatter, rank in registers)
    hipMemsetAsync(count, 0, NN * sizeof(int), stream);
    void* args[] = { (void*)&src, (void*)&dst, (void*)&count,
                     (void*)&ofs, (void*)&pay, (void*)&sums };
    hipLaunchCooperativeKernel((const void*)k_csr, dim3(CSR_BLOCKS),
                               dim3(CSR_THREADS), args, 0, stream);

    // per-node softmax + aggregation (one wave per node)
    k_node<<<(NN * 64) / 256, 256, 0, stream>>>(z16, pay, s_src, s_dst, ofs, count, out);
}

// Round 6
// 209.151 us; speedup vs baseline: 2.9813x; 2.9813x over previous
//
#include <hip/hip_runtime.h>
#include <math.h>

#define NN   100000
#define NE   1600000
#define IND  128
#define OUTD 64

// ---------------- ws layout (4-byte words) ----------------
#define OFF_Z      0                          // NN*OUTD bf16 = NN*32 words
#define OFF_SSRC   (OFF_Z + NN * OUTD / 2)    // NN f32
#define OFF_SDST   (OFF_SSRC + NN)            // NN f32
#define OFF_COUNT  (OFF_SDST + NN)            // NN i32
#define OFF_OFS    (OFF_COUNT + NN)           // NN i32
#define OFF_RANK   (OFF_OFS + NN)             // NE i32
#define OFF_PAY    (OFF_RANK + NE)            // NE i32: src id, sorted by dst
#define OFF_SUMS   (OFF_PAY + NE)             // 128 i32
// total ~= 27 MB

#define SCAN_CHUNK 1024
#define SCAN_BLOCKS ((NN + SCAN_CHUNK - 1) / SCAN_CHUNK)  // 98

__device__ __forceinline__ unsigned short f32_to_bf16_rne(float x)
{
    unsigned int b = __float_as_uint(x);
    b += 0x7FFFu + ((b >> 16) & 1u);
    return (unsigned short)(b >> 16);
}

// ---------------- z = h@W (bf16 out), s_src = z.a_src, s_dst = z.a_dst ----------------
// Block = 256 threads = 64 rows x 4 col-groups of 16. h tile staged in LDS.
__global__ void __launch_bounds__(256) k_zs(
    const float* __restrict__ h, const float* __restrict__ W,
    const float* __restrict__ a, unsigned short* __restrict__ z16,
    float* __restrict__ s_src, float* __restrict__ s_dst)
{
    __shared__ float4 tile[64 * 33];      // 64 rows, 32 float4 + 1 pad
    int tid = threadIdx.x;
    int base = blockIdx.x * 64;

    const float4* hg = reinterpret_cast<const float4*>(h);
#pragma unroll
    for (int i = 0; i < 8; ++i) {
        int fidx = i * 256 + tid;         // 0..2047
        int r = fidx >> 5;
        int c = fidx & 31;
        float4 v = make_float4(0.f, 0.f, 0.f, 0.f);
        if (base + r < NN) v = hg[(base + r) * 32 + c];
        tile[r * 33 + c] = v;
    }
    __syncthreads();

    int row = tid & 63;
    int cg_ = tid >> 6;
    int cgu = __builtin_amdgcn_readfirstlane(cg_);
    const float* Wc = W + cgu * 16;

    float acc[16];
#pragma unroll
    for (int j = 0; j < 16; ++j) acc[j] = 0.f;

#pragma unroll 8
    for (int k4 = 0; k4 < 32; ++k4) {
        float4 hv = tile[row * 33 + k4];
        const float* w = Wc + k4 * 4 * OUTD;
#pragma unroll
        for (int kk = 0; kk < 4; ++kk) {
            float hk = (&hv.x)[kk];
#pragma unroll
            for (int j = 0; j < 16; ++j)
                acc[j] = fmaf(hk, w[kk * OUTD + j], acc[j]);
        }
    }

    float s1 = 0.f, s2 = 0.f;
#pragma unroll
    for (int j = 0; j < 16; ++j) {
        s1 = fmaf(acc[j], a[cgu * 16 + j], s1);
        s2 = fmaf(acc[j], a[OUTD + cgu * 16 + j], s2);
    }

    __syncthreads();
    float* red = reinterpret_cast<float*>(tile);
    red[tid] = s1;
    red[256 + tid] = s2;
    __syncthreads();
    if (tid < 64 && base + tid < NN) {
        float t1 = red[tid] + red[tid + 64] + red[tid + 128] + red[tid + 192];
        float t2 = red[256 + tid] + red[256 + tid + 64] + red[256 + tid + 128] + red[256 + tid + 192];
        s_src[base + tid] = t1;
        s_dst[base + tid] = t2;
    }

    // store bf16 z slice: 16 cols -> 8 packed uints -> 2 uint4 stores
    if (base + row < NN) {
        unsigned int u[8];
#pragma unroll
        for (int p = 0; p < 8; ++p) {
            unsigned int lo = f32_to_bf16_rne(acc[2 * p]);
            unsigned int hi = f32_to_bf16_rne(acc[2 * p + 1]);
            u[p] = lo | (hi << 16);
        }
        unsigned short* zp = z16 + (base + row) * OUTD + cgu * 16;
        uint4* z4 = reinterpret_cast<uint4*>(zp);
        z4[0] = make_uint4(u[0], u[1], u[2], u[3]);
        z4[1] = make_uint4(u[4], u[5], u[6], u[7]);
    }
}

// ---------------- CSR build ----------------
// hist + per-edge rank (rank written coalesced; atomic lives here, not in scatter)
__global__ void k_hist(const int* __restrict__ dst, int* __restrict__ count,
                       int* __restrict__ rank)
{
    int e = blockIdx.x * blockDim.x + threadIdx.x;
    if (e < NE) rank[e] = atomicAdd(&count[dst[e]], 1);
}

__global__ void __launch_bounds__(SCAN_CHUNK) k_scan1(
    const int* __restrict__ count, int* __restrict__ ofs, int* __restrict__ sums)
{
    __shared__ int tmp[SCAN_CHUNK];
    int t = threadIdx.x;
    int i = blockIdx.x * SCAN_CHUNK + t;
    int v = (i < NN) ? count[i] : 0;
    tmp[t] = v;
    __syncthreads();
    for (int off = 1; off < SCAN_CHUNK; off <<= 1) {
        int x = (t >= off) ? tmp[t - off] : 0;
        __syncthreads();
        tmp[t] += x;
        __syncthreads();
    }
    if (i < NN) ofs[i] = tmp[t] - v;            // exclusive within block
    if (t == SCAN_CHUNK - 1) sums[blockIdx.x] = tmp[t];
}

__global__ void __launch_bounds__(128) k_scan2(int* __restrict__ sums)
{
    __shared__ int tmp[128];
    int i = threadIdx.x;
    int v = (i < SCAN_BLOCKS) ? sums[i] : 0;
    tmp[i] = v;
    __syncthreads();
    for (int off = 1; off < 128; off <<= 1) {
        int x = (i >= off) ? tmp[i - off] : 0;
        __syncthreads();
        tmp[i] += x;
        __syncthreads();
    }
    if (i < SCAN_BLOCKS) sums[i] = tmp[i] - v;  // exclusive block offsets
}

__global__ void __launch_bounds__(SCAN_CHUNK) k_scan3(
    int* __restrict__ ofs, const int* __restrict__ sums)
{
    int i = blockIdx.x * SCAN_CHUNK + threadIdx.x;
    if (i < NN) ofs[i] += sums[blockIdx.x];
}

// atomic-free scatter: one 4B random store per edge
__global__ void k_scatter(const int* __restrict__ src, const int* __restrict__ dst,
                          const int* __restrict__ ofs, const int* __restrict__ rank,
                          int* __restrict__ pay)
{
    int e = blockIdx.x * blockDim.x + threadIdx.x;
    if (e < NE) {
        int pos = ofs[dst[e]] + rank[e];
        pay[pos] = src[e];
    }
}

// ---------------- per-node softmax + aggregate (one wave per node) ----------------
__global__ void __launch_bounds__(256) k_node(
    const unsigned short* __restrict__ z16, const int* __restrict__ pay,
    const float* __restrict__ s_src, const float* __restrict__ s_dst,
    const int* __restrict__ ofs, const int* __restrict__ count,
    float* __restrict__ out)
{
    int gtid = blockIdx.x * 256 + threadIdx.x;
    int w = gtid >> 6;          // node id
    int lane = threadIdx.x & 63;
    if (w >= NN) return;

    int d = count[w];
    int start = ofs[w];
    if (d == 0) {
        out[w * OUTD + lane] = 0.f;
        return;
    }
    float sdst = s_dst[w];

    float acc = 0.f;            // lane owns output column `lane`
    float m = -INFINITY, l = 0.f;

    for (int c = 0; c < d; c += 64) {
        int rem = d - c; if (rem > 64) rem = 64;

        float ev = -INFINITY;
        int rowoff = 0;
        if (lane < rem) {
            int sid = pay[start + c + lane];     // coalesced 4B
            rowoff = sid * OUTD;
            float e0 = s_src[sid] + sdst;        // random 4B gather, L2-resident
            ev = e0 > 0.f ? e0 : 0.01f * e0;     // leaky_relu
        }

        float cmax = ev;
#pragma unroll
        for (int mm = 32; mm; mm >>= 1) cmax = fmaxf(cmax, __shfl_xor(cmax, mm, 64));
        float newm = fmaxf(m, cmax);
        float scale = __expf(m - newm);          // first chunk: exp(-inf)=0
        float ex = (lane < rem) ? __expf(ev - newm) : 0.f;
        float csum = ex;
#pragma unroll
        for (int mm = 32; mm; mm >>= 1) csum += __shfl_xor(csum, mm, 64);
        l = l * scale + csum;
        acc *= scale;
        m = newm;

        // aggregate chunk: 8-way unrolled bf16 gather of z rows
        int t = 0;
        for (; t + 8 <= rem; t += 8) {
            int r0 = __shfl(rowoff, t + 0, 64), r1 = __shfl(rowoff, t + 1, 64);
            int r2 = __shfl(rowoff, t + 2, 64), r3 = __shfl(rowoff, t + 3, 64);
            int r4 = __shfl(rowoff, t + 4, 64), r5 = __shfl(rowoff, t + 5, 64);
            int r6 = __shfl(rowoff, t + 6, 64), r7 = __shfl(rowoff, t + 7, 64);
            float e0 = __shfl(ex, t + 0, 64), e1 = __shfl(ex, t + 1, 64);
            float e2 = __shfl(ex, t + 2, 64), e3 = __shfl(ex, t + 3, 64);
            float e4 = __shfl(ex, t + 4, 64), e5 = __shfl(ex, t + 5, 64);
            float e6 = __shfl(ex, t + 6, 64), e7 = __shfl(ex, t + 7, 64);
            float v0 = __uint_as_float((unsigned int)z16[r0 + lane] << 16);
            float v1 = __uint_as_float((unsigned int)z16[r1 + lane] << 16);
            float v2 = __uint_as_float((unsigned int)z16[r2 + lane] << 16);
            float v3 = __uint_as_float((unsigned int)z16[r3 + lane] << 16);
            float v4 = __uint_as_float((unsigned int)z16[r4 + lane] << 16);
            float v5 = __uint_as_float((unsigned int)z16[r5 + lane] << 16);
            float v6 = __uint_as_float((unsigned int)z16[r6 + lane] << 16);
            float v7 = __uint_as_float((unsigned int)z16[r7 + lane] << 16);
            acc = fmaf(e0, v0, acc); acc = fmaf(e1, v1, acc);
            acc = fmaf(e2, v2, acc); acc = fmaf(e3, v3, acc);
            acc = fmaf(e4, v4, acc); acc = fmaf(e5, v5, acc);
            acc = fmaf(e6, v6, acc); acc = fmaf(e7, v7, acc);
        }
        for (; t < rem; ++t) {
            int r = __shfl(rowoff, t, 64);
            float e0 = __shfl(ex, t, 64);
            float v = __uint_as_float((unsigned int)z16[r + lane] << 16);
            acc = fmaf(e0, v, acc);
        }
    }

    out[w * OUTD + lane] = acc * (1.f / l);
}

// ---------------- launcher ----------------
extern "C" void kernel_launch(void* const* d_in, const int* in_sizes, int n_in,
                              void* d_out, int out_size, void* d_ws, size_t ws_size,
                              hipStream_t stream)
{
    const float* h   = (const float*)d_in[0];
    const float* W   = (const float*)d_in[1];
    const float* a   = (const float*)d_in[2];
    const int*   src = (const int*)d_in[3];
    const int*   dst = (const int*)d_in[4];
    float* out = (float*)d_out;

    int* ws_i = (int*)d_ws;

    unsigned short* z16 = (unsigned short*)(ws_i + OFF_Z);
    float* s_src  = (float*)(ws_i + OFF_SSRC);
    float* s_dst  = (float*)(ws_i + OFF_SDST);
    int*   count  = ws_i + OFF_COUNT;
    int*   ofs    = ws_i + OFF_OFS;
    int*   rank   = ws_i + OFF_RANK;
    int*   pay    = ws_i + OFF_PAY;
    int*   sums   = ws_i + OFF_SUMS;

    // z (bf16), s_src, s_dst
    k_zs<<<(NN + 63) / 64, 256, 0, stream>>>(h, W, a, z16, s_src, s_dst);

    // CSR by dst (separate kernels — cooperative fusion regressed in R5)
    hipMemsetAsync(count, 0, NN * sizeof(int), stream);
    k_hist<<<(NE + 255) / 256, 256, 0, stream>>>(dst, count, rank);
    k_scan1<<<SCAN_BLOCKS, SCAN_CHUNK, 0, stream>>>(count, ofs, sums);
    k_scan2<<<1, 128, 0, stream>>>(sums);
    k_scan3<<<SCAN_BLOCKS, SCAN_CHUNK, 0, stream>>>(ofs, sums);
    k_scatter<<<(NE + 255) / 256, 256, 0, stream>>>(src, dst, ofs, rank, pay);

    // per-node softmax + aggregation (one wave per node)
    k_node<<<(NN * 64) / 256, 256, 0, stream>>>(z16, pay, s_src, s_dst, ofs, count, out);
}